// Round 9
// baseline (386.570 us; speedup 1.0000x reference)
//
#include <hip/hip_runtime.h>
#include <hip/hip_bf16.h>

typedef __hip_bfloat16 bf16;
typedef unsigned short u16;

#define NC 8192
#define NF 32768
#define KNN 16
#define NPW 8                       // points per wave
#define FMAXV 3.402823466e+38f

__device__ __forceinline__ float bfbits2f(u16 u){
  union { unsigned u; float f; } x; x.u = ((unsigned)u) << 16; return x.f;
}
// monotone bijection f32 -> u32 (order-preserving for all finite floats)
__device__ __forceinline__ unsigned fmap(float f){
  unsigned b = __float_as_uint(f);
  return b ^ ((unsigned)((int)b >> 31) | 0x80000000u);
}
__device__ __forceinline__ float funmap(unsigned u){
  unsigned b = (u & 0x80000000u) ? (u ^ 0x80000000u) : ~u;
  return __uint_as_float(b);
}
// full-wave64 f32 sum via DPP; total lands in lane 63 (old=0 makes invalid lanes add 0)
__device__ __forceinline__ float wave_sum63(float x){
  float s = x;
  s += __int_as_float(__builtin_amdgcn_update_dpp(0, __float_as_int(s), 0x111, 0xF, 0xF, true));  // row_shr:1
  s += __int_as_float(__builtin_amdgcn_update_dpp(0, __float_as_int(s), 0x112, 0xF, 0xF, true));  // row_shr:2
  s += __int_as_float(__builtin_amdgcn_update_dpp(0, __float_as_int(s), 0x114, 0xF, 0xF, true));  // row_shr:4
  s += __int_as_float(__builtin_amdgcn_update_dpp(0, __float_as_int(s), 0x118, 0xF, 0xF, true));  // row_shr:8
  s += __int_as_float(__builtin_amdgcn_update_dpp(0, __float_as_int(s), 0x142, 0xF, 0xF, false)); // row_bcast:15
  s += __int_as_float(__builtin_amdgcn_update_dpp(0, __float_as_int(s), 0x143, 0xF, 0xF, false)); // row_bcast:31
  return s;
}
__device__ __forceinline__ float rdlane_f(float v, int l){
  return __int_as_float(__builtin_amdgcn_readlane(__float_as_int(v), l));
}

// ---------- k_prep2: weight products + pos4 + MLP swizzles (grid 321) ----------
__global__ __launch_bounds__(256) void k_prep2(const float* __restrict__ dpos,
                                               const float* __restrict__ Wk,
                                               const float* __restrict__ Wv,
                                               const float* __restrict__ Wq,
                                               const float* __restrict__ W1,
                                               const float* __restrict__ W2,
                                               const float* __restrict__ bk,
                                               const float* __restrict__ bv,
                                               const float* __restrict__ bq,
                                               float4* __restrict__ pos4,
                                               float4* __restrict__ W1eSa, float4* __restrict__ W1eSb,
                                               float4* __restrict__ W2Sa,  float4* __restrict__ W2Sb,
                                               float* __restrict__ WkqS,   float* __restrict__ WvuS,
                                               float* __restrict__ bkq,    float* __restrict__ bvu,
                                               float* __restrict__ wbq,    float* __restrict__ sbq){
  __shared__ float red[256];
  int b = blockIdx.x, t = threadIdx.x;
  if (b < 128){
    int c = b;
    float acc = 0.f;
    for (int j = 0; j < 256; ++j)
      acc = fmaf(Wk[(size_t)j * 256 + t], Wq[(size_t)j * 128 + c], acc);
    WkqS[(size_t)((t >> 2) * 128 + c) * 4 + (t & 3)] = acc;
    red[t] = bk[t] * Wq[(size_t)t * 128 + c];
    __syncthreads();
    for (int s = 128; s > 0; s >>= 1){ if (t < s) red[t] += red[t + s]; __syncthreads(); }
    if (t == 0) bkq[c] = red[0];
  } else if (b < 256){
    int h = b - 128;
    float acc = 0.f;
    for (int c2 = 0; c2 < 256; ++c2)
      acc = fmaf(Wv[(size_t)c2 * 256 + t], W1[(size_t)h * 384 + c2], acc);
    WvuS[(size_t)((t >> 2) * 128 + h) * 4 + (t & 3)] = acc;
    red[t] = bv[t] * W1[(size_t)h * 384 + t];
    __syncthreads();
    for (int s = 128; s > 0; s >>= 1){ if (t < s) red[t] += red[t + s]; __syncthreads(); }
    if (t == 0) bvu[h] = red[0];
  } else if (b == 256){
    float acc = 0.f;
    for (int j = 0; j < 256; ++j)
      acc = fmaf(Wk[(size_t)j * 256 + t], bq[j], acc);
    wbq[t] = acc;
    red[t] = bk[t] * bq[t];
    __syncthreads();
    for (int s = 128; s > 0; s >>= 1){ if (t < s) red[t] += red[t + s]; __syncthreads(); }
    if (t == 0) sbq[0] = red[0];
  } else {
    int g = (b - 257) * 256 + t;   // [0, 16384)
    if (g < 8192){
      float x = dpos[g * 3 + 0], y = dpos[g * 3 + 1], z = dpos[g * 3 + 2];
      float dd = __fadd_rn(__fadd_rn(__fmul_rn(x,x), __fmul_rn(y,y)), __fmul_rn(z,z));
      pos4[g] = make_float4(x, y, z, dd * 0.5f);
    } else if (g < 10240){
      int f = g - 8192; int c4 = f >> 6, jg = f & 63;
      W1eSa[f] = ((const float4*)(W1 + (size_t)(2 * jg) * 384 + 256))[c4];
    } else if (g < 12288){
      int f = g - 10240; int c4 = f >> 6, jg = f & 63;
      W1eSb[f] = ((const float4*)(W1 + (size_t)(2 * jg + 1) * 384 + 256))[c4];
    } else if (g < 14336){
      int f = g - 12288; int c4 = f >> 6, jg = f & 63;
      W2Sa[f] = ((const float4*)(W2 + (size_t)(2 * jg) * 128))[c4];
    } else {
      int f = g - 14336; int c4 = f >> 6, jg = f & 63;
      W2Sb[f] = ((const float4*)(W2 + (size_t)(2 * jg + 1) * 128))[c4];
    }
  }
}

// ---------- k_dec: Zd = df@Wkq + bkq, Ud = df@Wvu + bvu, bqK = df@wbq + sbq ----------
__global__ __launch_bounds__(256) void k_dec(const float* __restrict__ df,
                                             const float4* __restrict__ WkqS,
                                             const float4* __restrict__ WvuS,
                                             const float* __restrict__ bkq,
                                             const float* __restrict__ bvu,
                                             const float* __restrict__ wbq,
                                             const float* __restrict__ sbq,
                                             bf16* __restrict__ Zd, bf16* __restrict__ Ud,
                                             float* __restrict__ bqK){
  __shared__ float part[16][16];
  int t = threadIdx.x;
  int g0 = blockIdx.x * 16;
  int half = __builtin_amdgcn_readfirstlane(t >> 7);
  int c = t & 127;
  const float4* W = half ? WvuS : WkqS;
  float acc[16];
  #pragma unroll
  for (int p = 0; p < 16; ++p) acc[p] = 0.f;
  for (int j4 = 0; j4 < 64; ++j4){
    float4 w = W[j4 * 128 + c];
    #pragma unroll
    for (int p = 0; p < 16; ++p){
      float4 a = ((const float4*)(df + (size_t)(g0 + p) * 256))[j4];
      acc[p] += w.x*a.x + w.y*a.y + w.z*a.z + w.w*a.w;
    }
  }
  float bias = half ? bvu[c] : bkq[c];
  bf16* dst = half ? Ud : Zd;
  #pragma unroll
  for (int p = 0; p < 16; ++p)
    dst[(size_t)(g0 + p) * 128 + c] = __float2bfloat16(acc[p] + bias);
  {
    int r = t >> 4, seg = t & 15;
    float s = 0.f;
    const float* dr = df + (size_t)(g0 + r) * 256 + seg * 16;
    const float* wq = wbq + seg * 16;
    #pragma unroll
    for (int e = 0; e < 16; ++e) s = fmaf(dr[e], wq[e], s);
    part[r][seg] = s;
  }
  __syncthreads();
  if (t < 16){
    float s = sbq[0];
    #pragma unroll
    for (int seg = 0; seg < 16; ++seg) s += part[t][seg];
    bqK[g0 + t] = s;
  }
}

// ---------- k_fused: KNN + attention + MLP + LayerNorm + tail, one kernel ----------
// Each wave independently owns 8 points and scans all 8192 candidates.
// tau per point: ballot-radix 16th-smallest of the 64 lane-minima (no DS).
// Scores: DPP wave sums + readlane broadcasts (no shuffles). h stays in registers
// between attention and MLP stage 1; transpose via 2KB wave-private LDS for stage 2.
__global__ __launch_bounds__(256) void k_fused(const float* __restrict__ epos,
                                               const float4* __restrict__ pos4,
                                               const float* __restrict__ ef,
                                               const bf16* __restrict__ Zd,
                                               const bf16* __restrict__ Ud,
                                               const float* __restrict__ bqK,
                                               const float4* __restrict__ W1eSa,
                                               const float4* __restrict__ W1eSb,
                                               const float* __restrict__ b1,
                                               const float4* __restrict__ W2Sa,
                                               const float4* __restrict__ W2Sb,
                                               const float* __restrict__ b2,
                                               const float* __restrict__ lng,
                                               const float* __restrict__ lnb,
                                               const int* __restrict__ lab,
                                               float* __restrict__ out){
  __shared__ unsigned lu[4][NPW][64];
  __shared__ int      li[4][NPW][64];
  __shared__ int      cnt[4][NPW];
  __shared__ float    hb[4][128];

  int t = threadIdx.x, lane = t & 63, w = t >> 6;
  // fused tail passthrough (blocks 0..127 cover NF)
  {
    int gid = blockIdx.x * 256 + t;
    if (gid < NF){
      float* op = out + (size_t)NF * 128;
      op[gid * 3 + 0] = epos[gid * 3 + 0];
      op[gid * 3 + 1] = epos[gid * 3 + 1];
      op[gid * 3 + 2] = epos[gid * 3 + 2];
      out[(size_t)NF * 128 + (size_t)NF * 3 + gid] = (float)lab[gid];
    }
  }
  int n0 = (blockIdx.x * 4 + w) * NPW;
  float nex[NPW], ney[NPW], nez[NPW];
  #pragma unroll
  for (int p = 0; p < NPW; ++p){
    nex[p] = -epos[(n0 + p) * 3 + 0];
    ney[p] = -epos[(n0 + p) * 3 + 1];
    nez[p] = -epos[(n0 + p) * 3 + 2];
  }
  if (lane < NPW) cnt[w][lane] = 0;

  // ---- PASS A: per-lane minima of val = dd/2 - e.d over lane's 128 candidates
  float vmin[NPW];
  #pragma unroll
  for (int p = 0; p < NPW; ++p) vmin[p] = FMAXV;
  #pragma unroll 4
  for (int s = 0; s < 128; ++s){
    float4 P = pos4[s * 64 + lane];
    #pragma unroll
    for (int p = 0; p < NPW; ++p){
      float val = fmaf(nez[p], P.z, fmaf(ney[p], P.y, fmaf(nex[p], P.x, P.w)));
      vmin[p] = fminf(vmin[p], val);
    }
  }
  // ---- tau0: ballot-radix 16th smallest of the 64 lane-minima (20 high bits, round up)
  float tau0[NPW];
  #pragma unroll
  for (int p = 0; p < NPW; ++p){
    unsigned u = fmap(vmin[p]);
    unsigned pref = 0; int kk = 16; bool alive = true;
    #pragma unroll
    for (int bIt = 31; bIt >= 12; --bIt){
      bool zero = alive && ((u & (1u << bIt)) == 0u);
      int c = __popcll(__ballot(zero));
      if (c >= kk){ alive = zero; }
      else { kk -= c; alive = alive && !zero; pref |= (1u << bIt); }
    }
    tau0[p] = funmap(pref | 0xFFFu);   // >= exact 16th lane-min => valid bound
  }
  __syncthreads();   // cnt init visible

  // ---- PASS B: filtered append (identical val expression as pass A)
  #pragma unroll 2
  for (int s = 0; s < 128; ++s){
    float4 P = pos4[s * 64 + lane];
    int cand = s * 64 + lane;
    #pragma unroll
    for (int p = 0; p < NPW; ++p){
      float val = fmaf(nez[p], P.z, fmaf(ney[p], P.y, fmaf(nex[p], P.x, P.w)));
      if (val <= tau0[p]){
        int slot = atomicAdd(&cnt[w][p], 1);
        if (slot < 64){ lu[w][p][slot] = fmap(val); li[w][p][slot] = cand; }
      }
    }
  }
  __syncthreads();

  float2 b1v = *(const float2*)(b1 + lane * 2);
  float2 b2v = *(const float2*)(b2 + lane * 2);
  float2 lgv = *(const float2*)(lng + lane * 2);
  float2 lbv = *(const float2*)(lnb + lane * 2);

  for (int p = 0; p < NPW; ++p){
    int n = n0 + p;
    int c = cnt[w][p]; if (c > 64) c = 64;
    unsigned v = (lane < c) ? lu[w][p][lane] : 0xFFFFFFFFu;
    int     id = (lane < c) ? li[w][p][lane] : 0x7fffffff;
    // exact (u, idx) bitonic sort ascending -> top-16 in lanes 0..15 (jax tie order)
    #pragma unroll
    for (int k = 2; k <= 64; k <<= 1){
      #pragma unroll
      for (int j = k >> 1; j > 0; j >>= 1){
        unsigned pv = __shfl_xor(v, j);
        int     pid = __shfl_xor(id, j);
        bool keepmin = ((lane & j) == 0) == ((lane & k) == 0);
        bool pless = (pv < v) || (pv == v && pid < id);
        bool take = keepmin ? pless : !pless;
        if (take){ v = pv; id = pid; }
      }
    }
    // scores (DPP sums, readlane broadcasts)
    float2 eu = *(const float2*)(ef + (size_t)n * 128 + lane * 2);
    float sc[KNN];
    int ika[KNN];
    #pragma unroll
    for (int k = 0; k < KNN; ++k){
      int ik = __builtin_amdgcn_readlane(id, k);
      ika[k] = ik;
      ushort2 zu = *(const ushort2*)((const u16*)Zd + (size_t)ik * 128 + lane * 2);
      float pr = eu.x * bfbits2f(zu.x) + eu.y * bfbits2f(zu.y);
      float tot = rdlane_f(wave_sum63(pr), 63);
      sc[k] = (tot + bqK[ik]) * (1.0f / 16.0f);
    }
    // softmax on uniform registers
    float mx = sc[0];
    #pragma unroll
    for (int k = 1; k < KNN; ++k) mx = fmaxf(mx, sc[k]);
    float e[KNN], l = 0.f;
    #pragma unroll
    for (int k = 0; k < KNN; ++k){ e[k] = __expf(sc[k] - mx); l += e[k]; }
    float invl = 1.0f / l;
    // hidden aggregation: lane holds channels (2*lane, 2*lane+1) of hagg == MLP1 layout
    float a0 = 0.f, a1 = 0.f;
    #pragma unroll
    for (int k = 0; k < KNN; ++k){
      float wk = e[k] * invl;
      ushort2 uu = *(const ushort2*)((const u16*)Ud + (size_t)ika[k] * 128 + lane * 2);
      a0 = fmaf(wk, bfbits2f(uu.x), a0);
      a1 = fmaf(wk, bfbits2f(uu.y), a1);
    }
    // MLP stage 1: h = relu(hagg + W1e@ef + b1)
    float h0 = a0 + b1v.x, h1 = a1 + b1v.y;
    const float4* efr = (const float4*)(ef + (size_t)n * 128);
    #pragma unroll 4
    for (int c4 = 0; c4 < 32; ++c4){
      float4 wa = W1eSa[c4 * 64 + lane];
      float4 wb = W1eSb[c4 * 64 + lane];
      float4 x = efr[c4];
      h0 += wa.x*x.x + wa.y*x.y + wa.z*x.z + wa.w*x.w;
      h1 += wb.x*x.x + wb.y*x.y + wb.z*x.z + wb.w*x.w;
    }
    h0 = fmaxf(h0, 0.f); h1 = fmaxf(h1, 0.f);
    // transpose h through wave-private LDS row
    *(float2*)(&hb[w][lane * 2]) = make_float2(h0, h1);
    // MLP stage 2: up = W2@h + b2 (hb reads are wave-uniform broadcasts)
    float u0 = b2v.x, u1 = b2v.y;
    const float4* hr = (const float4*)(&hb[w][0]);
    #pragma unroll 4
    for (int c4 = 0; c4 < 32; ++c4){
      float4 wa = W2Sa[c4 * 64 + lane];
      float4 wb = W2Sb[c4 * 64 + lane];
      float4 x = hr[c4];
      u0 += wa.x*x.x + wa.y*x.y + wa.z*x.z + wa.w*x.w;
      u1 += wb.x*x.x + wb.y*x.y + wb.z*x.z + wb.w*x.w;
    }
    // LayerNorm via DPP wave sums
    float mu = rdlane_f(wave_sum63(u0 + u1), 63) * (1.0f / 128.0f);
    float m2 = rdlane_f(wave_sum63(u0 * u0 + u1 * u1), 63) * (1.0f / 128.0f);
    float var = m2 - mu * mu;
    float rs = rsqrtf(fmaxf(var, 0.f) + 1e-5f);
    *(float2*)(out + (size_t)n * 128 + lane * 2) =
        make_float2((u0 - mu) * rs * lgv.x + lbv.x,
                    (u1 - mu) * rs * lgv.y + lbv.y);
  }
}

extern "C" void kernel_launch(void* const* d_in, const int* in_sizes, int n_in,
                              void* d_out, int out_size, void* d_ws, size_t ws_size,
                              hipStream_t stream){
  const float* df   = (const float*)d_in[0];
  const float* dpos = (const float*)d_in[1];
  const float* ef   = (const float*)d_in[2];
  const float* epos = (const float*)d_in[3];
  const int*   lab  = (const int*)d_in[4];
  const float* Wq = (const float*)d_in[5];
  const float* bq = (const float*)d_in[6];
  const float* Wk = (const float*)d_in[7];
  const float* bk = (const float*)d_in[8];
  const float* Wv = (const float*)d_in[9];
  const float* bv = (const float*)d_in[10];
  const float* W1 = (const float*)d_in[11];
  const float* b1 = (const float*)d_in[12];
  const float* W2 = (const float*)d_in[13];
  const float* b2 = (const float*)d_in[14];
  const float* lng = (const float*)d_in[15];
  const float* lnb = (const float*)d_in[16];
  float* out = (float*)d_out;

  // workspace (~4.6 MB)
  char* wsb = (char*)d_ws;
  float4* pos4  = (float4*)(wsb);                    // 128 KB
  bf16*   Zd    = (bf16*)(wsb + 131072);             // 2 MB
  bf16*   Ud    = (bf16*)(wsb + 2228224);            // 2 MB
  float*  bqK   = (float*)(wsb + 4325376);           // 32 KB
  float4* W1eSa = (float4*)(wsb + 4358144);          // 32 KB
  float4* W1eSb = (float4*)(wsb + 4390912);          // 32 KB
  float4* W2Sa  = (float4*)(wsb + 4423680);          // 32 KB
  float4* W2Sb  = (float4*)(wsb + 4456448);          // 32 KB
  float*  WkqS  = (float*)(wsb + 4489216);           // 128 KB
  float*  WvuS  = (float*)(wsb + 4620288);           // 128 KB
  float*  bkq   = (float*)(wsb + 4751360);           // 512 B
  float*  bvu   = (float*)(wsb + 4751872);           // 512 B
  float*  wbq   = (float*)(wsb + 4752384);           // 1 KB
  float*  sbq   = (float*)(wsb + 4753408);           // 4 B

  k_prep2<<<321, 256, 0, stream>>>(dpos, Wk, Wv, Wq, W1, W2, bk, bv, bq,
                                   pos4, W1eSa, W1eSb, W2Sa, W2Sb,
                                   WkqS, WvuS, bkq, bvu, wbq, sbq);
  k_dec  <<<NC / 16, 256, 0, stream>>>(df, (const float4*)WkqS, (const float4*)WvuS,
                                       bkq, bvu, wbq, sbq, Zd, Ud, bqK);
  k_fused<<<NF / 32, 256, 0, stream>>>(epos, pos4, ef, Zd, Ud, bqK,
                                       W1eSa, W1eSb, b1, W2Sa, W2Sb, b2,
                                       lng, lnb, lab, out);
  (void)in_sizes; (void)n_in; (void)out_size; (void)ws_size;
}